// Round 18
// baseline (1092.000 us; speedup 1.0000x reference)
//
#include <hip/hip_runtime.h>
#include <hip/hip_bf16.h>

#define DEV __device__ __forceinline__

using bf16 = __hip_bfloat16;
typedef __attribute__((ext_vector_type(8))) short short8v;  // 8 bf16 = 4 VGPRs
typedef __attribute__((ext_vector_type(4))) float f32x4;

constexpr int Bq = 16, Tq = 1024, Eq = 1024, Gq = 4, Nq = 8, Dq = 128, Vq = 2048;
constexpr int M1 = Bq * Tq;        // 16384
constexpr int N1q = Gq * Nq * Dq;  // 4096
constexpr int K1 = Eq;             // 1024
constexpr int K2 = Nq * Dq;        // 1024
constexpr int N2 = Vq;             // 2048

DEV unsigned short bfu(float x) {
  union { bf16 h; unsigned short u; } cv;
  cv.h = __float2bfloat16(x);
  return cv.u;
}

DEV float rcp_(float x) { return __builtin_amdgcn_rcpf(x); }
DEV float sigm(float x) { return rcp_(1.0f + __expf(-x)); }
DEV float tanh_(float x) { return fmaf(2.0f, rcp_(1.0f + __expf(-2.0f * x)), -1.0f); }

// async global->LDS, 16B per lane; LDS dest is wave-uniform base + lane*16
#define GLD16(gp, lp)                                                       \
  __builtin_amdgcn_global_load_lds(                                        \
      (const __attribute__((address_space(1))) void*)(gp),                 \
      (__attribute__((address_space(3))) void*)(lp), 16, 0, 0)

// ---------------------------------------------------------------------------
// Prep kernels
// ---------------------------------------------------------------------------
__global__ __launch_bounds__(256) void cast_f32_bf16(const float* __restrict__ s,
                                                     bf16* __restrict__ d, int n4) {
  const int i = blockIdx.x * 256 + threadIdx.x;
  if (i >= n4) return;
  const float4 v = ((const float4*)s)[i];
  ushort4 u;
  u.x = bfu(v.x); u.y = bfu(v.y); u.z = bfu(v.z); u.w = bfu(v.w);
  ((ushort4*)d)[i] = u;
}

// W_in[k][c] f32 (c = g*1024+n*128+dd) -> WiT_perm[n*512 + dd*4 + g][k] bf16.
__global__ __launch_bounds__(256) void transpose_cast_perm(const float* __restrict__ s,
                                                           bf16* __restrict__ d,
                                                           int SK, int SN) {
  __shared__ float t[32][33];
  const int n0 = blockIdx.x * 32, k0 = blockIdx.y * 32;
  const int tx = threadIdx.x & 31, ty = threadIdx.x >> 5;  // ty: 0..7
#pragma unroll
  for (int i = 0; i < 32; i += 8)
    t[ty + i][tx] = s[(size_t)(k0 + ty + i) * SN + n0 + tx];
  __syncthreads();
#pragma unroll
  for (int i = 0; i < 32; i += 8) {
    const int c = n0 + ty + i;
    const int g = c >> 10, n = (c >> 7) & 7, dd = c & 127;
    const int rp = n * 512 + dd * 4 + g;
    d[(size_t)rp * SK + k0 + tx] = __float2bfloat16(t[tx][ty + i]);
  }
}

// ---------------------------------------------------------------------------
// bf16 MFMA GEMM, m97 structure: C[M,N] = A[M,K] @ Bt[N,K]^T
// MODE 0: f32 out + bias (natural).
// MODE 3: bf16 out + bias folded, permuted-packed (coalesced stores).
// ---------------------------------------------------------------------------
template <int MODE>
__global__ __launch_bounds__(256) void gemm_bt(const bf16* __restrict__ A,
                                               const bf16* __restrict__ Bt,
                                               void* __restrict__ Cout,
                                               const float* __restrict__ bp,
                                               int K, int N) {
  __shared__ bf16 As[128 * 32];
  __shared__ bf16 Bs[128 * 32];
  const int m0 = blockIdx.y * 128, n0 = blockIdx.x * 128;
  const int tid = threadIdx.x;
  const int lane = tid & 63, w = tid >> 6;
  const int wm = w >> 1, wn = w & 1;

  const int srow = lane >> 2, scol = (lane & 3) * 8;
  const int ca = w * 2;
  const bf16* Ag0 = A + (size_t)(m0 + ca * 16 + srow) * K + scol;
  const bf16* Ag1 = Ag0 + (size_t)16 * K;
  const bf16* Bg0 = Bt + (size_t)(n0 + ca * 16 + srow) * K + scol;
  const bf16* Bg1 = Bg0 + (size_t)16 * K;
  bf16* Al0 = As + ca * 512;
  bf16* Al1 = Al0 + 512;
  bf16* Bl0 = Bs + ca * 512;
  bf16* Bl1 = Bl0 + 512;

  f32x4 acc[4][4] = {};

  const int rr = lane & 15;
  const int kb = (lane >> 4) * 8;

  for (int k0 = 0; k0 < K; k0 += 32) {
    GLD16(Ag0 + k0, Al0);
    GLD16(Ag1 + k0, Al1);
    GLD16(Bg0 + k0, Bl0);
    GLD16(Bg1 + k0, Bl1);
    __syncthreads();
    short8v af[4], bfr[4];
#pragma unroll
    for (int i = 0; i < 4; ++i) {
      af[i]  = *(const short8v*)&As[(wm * 64 + i * 16 + rr) * 32 + kb];
      bfr[i] = *(const short8v*)&Bs[(wn * 64 + i * 16 + rr) * 32 + kb];
    }
#pragma unroll
    for (int i = 0; i < 4; ++i)
#pragma unroll
      for (int j = 0; j < 4; ++j)
        acc[i][j] = __builtin_amdgcn_mfma_f32_16x16x32_bf16(af[i], bfr[j], acc[i][j], 0, 0, 0);
    __syncthreads();
  }

  const int crow = (lane >> 4) * 4, ccol = lane & 15;
  if constexpr (MODE == 3) {
    // permuted col pc = n*512 + dd*4 + g; output row (b,t).
    bf16* C = (bf16*)Cout;
#pragma unroll
    for (int i = 0; i < 4; ++i)
#pragma unroll
      for (int j = 0; j < 4; ++j) {
        const int pc = n0 + wn * 64 + j * 16 + ccol;
        const int n = pc >> 9, gd = pc & 511;
        const int g = gd & 3, dd = gd >> 2;
        const float bvj = bp[(g * 8 + n) * 128 + dd];
#pragma unroll
        for (int jj = 0; jj < 4; ++jj) {
          const int row = m0 + wm * 64 + i * 16 + crow + jj;
          const int b = row >> 10, t = row & 1023;
          const size_t idx = (((size_t)(b * 8 + n) << 10) + t) * 512 + gd;
          C[idx] = __float2bfloat16(acc[i][j][jj] + bvj);
        }
      }
  } else {
    float* C = (float*)Cout;
    float bv[4];
#pragma unroll
    for (int j = 0; j < 4; ++j) bv[j] = bp[n0 + wn * 64 + j * 16 + ccol];
#pragma unroll
    for (int i = 0; i < 4; ++i)
#pragma unroll
      for (int j = 0; j < 4; ++j) {
        const size_t base =
            (size_t)(m0 + wm * 64 + i * 16 + crow) * N + (n0 + wn * 64 + j * 16 + ccol);
#pragma unroll
        for (int jj = 0; jj < 4; ++jj)
          C[base + (size_t)jj * N] = acc[i][j][jj] + bv[j];
      }
  }
}

// ---------------------------------------------------------------------------
// LSTM recurrence, v15: v14 structure at DOUBLE per-CU occupancy.
// 16 WGs x 1024 threads (16 waves, 4 waves/SIMD via amdgpu_waves_per_eu(4,4)
// -> 128-VGPR budget, no spill for our ~100-VGPR body; r8/r9's failure was
// the 64-VGPR default at 1024 threads).
// Waves 0-7: group gid=2*wg; waves 8-15: group 2*wg+1. Groups have separate
// hl buffers; the WG-wide barrier over-syncs (same cadence) but is correct.
// While one group's waves sit in MFMA/trans dependency chains, the other
// group's waves issue -> fills the measured 53% per-SIMD idle.
// ---------------------------------------------------------------------------
__global__ void __attribute__((amdgpu_flat_work_group_size(1024, 1024),
                               amdgpu_waves_per_eu(4, 4)))
lstm_mfma(const bf16* __restrict__ Wx, const float* __restrict__ R,
          bf16* __restrict__ h_all) {
  const int tid = threadIdx.x;
  const int w16 = tid >> 6, lane = tid & 63;
  const int half = w16 >> 3;       // group slot within WG
  const int wv = w16 & 7;          // wave within group
  const int gid = blockIdx.x * 2 + half;  // 0..31
  const int n = gid & 7, bq = gid >> 3;
  const int lg = lane >> 4, lc = lane & 15;
  const int bloc = lc & 3;     // local batch 0..3
  const int ci = lc >> 2;      // selected tile index
  const int dsite = 16 * wv + 4 * ci + lg;  // this lane's site d

  // A fragments (R): tile tau row lc -> gd = 64*wv+16*tau+lc; k = 32kf+8lg+j
  short8v Af[4][4];
#pragma unroll
  for (int tau = 0; tau < 4; ++tau) {
    const int gd = 64 * wv + 16 * tau + lc;
    const int g = gd & 3, d = gd >> 2;
    const float* rbase = R + ((size_t)(g * 8 + n) * 128 + d) * 128;
#pragma unroll
    for (int kf = 0; kf < 4; ++kf) {
      const float* rp = rbase + 32 * kf + 8 * lg;
      const float4 r0 = *(const float4*)rp;
      const float4 r1 = *(const float4*)(rp + 4);
      short8v bv;
      bv[0] = (short)bfu(r0.x); bv[1] = (short)bfu(r0.y);
      bv[2] = (short)bfu(r0.z); bv[3] = (short)bfu(r0.w);
      bv[4] = (short)bfu(r1.x); bv[5] = (short)bfu(r1.y);
      bv[6] = (short)bfu(r1.z); bv[7] = (short)bfu(r1.w);
      Af[tau][kf] = bv;
    }
  }

  // h LDS: [half][dbuf][b(4)][144] ushorts (pitch 288B)
  __shared__ __align__(16) unsigned short hl[2][2][4][144];
  for (int i = tid; i < 2 * 2 * 4 * 144; i += 1024) (&hl[0][0][0][0])[i] = 0;
  __syncthreads();

  // wx packed: Wx[((b*8+n)*1024+t)*512 + d*4 + g]
  const bf16* wxb =
      Wx + ((size_t)((bq * 4 + bloc) * 8 + n) << 10) * 512 + dsite * 4;
  // h_all[b*1024+t][n*128+d]
  bf16* hout = h_all + ((size_t)(bq * 4 + bloc) << 20) + n * 128 + dsite;

  // 4-deep static prefetch: one ushort4 (4 gates) per step
  ushort4 wxr[4];
#pragma unroll
  for (int u = 0; u < 4; ++u)
    wxr[u] = *(const ushort4*)(wxb + (size_t)u * 512);

  float c = 0.f;

  for (int t0 = 0; t0 < Tq; t0 += 4) {
#pragma unroll
    for (int u = 0; u < 4; ++u) {
      const int t = t0 + u;
      // B fragments: col lc -> h row (lc&3), k = 32kf+8lg+j
      const unsigned short* hb = &hl[half][t & 1][0][0];
      short8v Bf[4];
#pragma unroll
      for (int kf = 0; kf < 4; ++kf)
        Bf[kf] = *(const short8v*)(hb + bloc * 144 + kf * 32 + lg * 8);

      // capture this step's wx BEFORE the slot is overwritten (r11 lesson)
      const ushort4 wxc = wxr[u];

      // 4 independent MFMA tile chains, C-in = 0
      f32x4 acc[4];
#pragma unroll
      for (int tau = 0; tau < 4; ++tau) {
        acc[tau][0] = 0.f; acc[tau][1] = 0.f; acc[tau][2] = 0.f; acc[tau][3] = 0.f;
      }
#pragma unroll
      for (int kf = 0; kf < 4; ++kf)
#pragma unroll
        for (int tau = 0; tau < 4; ++tau)
          acc[tau] = __builtin_amdgcn_mfma_f32_16x16x32_bf16(Af[tau][kf], Bf[kf], acc[tau], 0, 0, 0);

      // prefetch wx for step t+4 into the SAME static slot (safe now)
      {
        const int tp = (t + 4 < Tq) ? (t + 4) : (Tq - 1);
        wxr[u] = *(const ushort4*)(wxb + (size_t)tp * 512);
      }

      // extract this lane's site (tile ci) + add wx; elements = gates i,f,z,o
      float pre0 = (ci & 2) ? ((ci & 1) ? acc[3][0] : acc[2][0])
                            : ((ci & 1) ? acc[1][0] : acc[0][0]);
      float pre1 = (ci & 2) ? ((ci & 1) ? acc[3][1] : acc[2][1])
                            : ((ci & 1) ? acc[1][1] : acc[0][1]);
      float pre2 = (ci & 2) ? ((ci & 1) ? acc[3][2] : acc[2][2])
                            : ((ci & 1) ? acc[1][2] : acc[0][2]);
      float pre3 = (ci & 2) ? ((ci & 1) ? acc[3][3] : acc[2][3])
                            : ((ci & 1) ? acc[1][3] : acc[0][3]);
      pre0 += __uint_as_float((unsigned)wxc.x << 16);
      pre1 += __uint_as_float((unsigned)wxc.y << 16);
      pre2 += __uint_as_float((unsigned)wxc.z << 16);
      pre3 += __uint_as_float((unsigned)wxc.w << 16);

      const float i_ = sigm(pre0);
      const float f_ = sigm(pre1);
      const float z_ = tanh_(pre2);
      const float o_ = sigm(pre3);
      c = f_ * c + i_ * z_;
      const float h = o_ * tanh_(c);
      const bf16 h16 = __float2bfloat16(h);

      hl[half][(t + 1) & 1][bloc][dsite] = ((const unsigned short*)&h16)[0];
      hout[(size_t)t << 10] = h16;

      // barrier WITHOUT vmcnt drain: only LDS visibility needed.
      __builtin_amdgcn_sched_barrier(0);
      asm volatile("s_waitcnt lgkmcnt(0)" ::: "memory");
      __builtin_amdgcn_sched_barrier(0);
      __builtin_amdgcn_s_barrier();
      __builtin_amdgcn_sched_barrier(0);
    }
  }
}

// ---------------------------------------------------------------------------
extern "C" void kernel_launch(void* const* d_in, const int* in_sizes, int n_in,
                              void* d_out, int out_size, void* d_ws, size_t ws_size,
                              hipStream_t stream) {
  const float* x_emb = (const float*)d_in[0];  // [16,1024,1024]
  const float* W_in  = (const float*)d_in[1];  // [1024,4096]
  const float* R     = (const float*)d_in[2];  // [4,8,128,128]
  const float* bias  = (const float*)d_in[3];  // [4,8,128]
  const float* W_prj = (const float*)d_in[4];  // [2048,1024]
  const float* b_prj = (const float*)d_in[5];  // [2048]

  char* ws = (char*)d_ws;
  bf16* xb  = (bf16*)ws;                               // 32 MB
  bf16* WiT = (bf16*)(ws + (size_t)M1 * K1 * 2);       //  8 MB (row-permuted)
  bf16* Wpb = WiT + (size_t)N1q * K1;                  //  4 MB
  bf16* H   = Wpb + (size_t)N2 * K2;                   // 32 MB
  bf16* Wx = (bf16*)d_out;  // 134 MB packed [(b*8+n)*1024+t][d*4+g]

  cast_f32_bf16<<<(M1 * K1 / 4 + 255) / 256, 256, 0, stream>>>(x_emb, xb, M1 * K1 / 4);
  transpose_cast_perm<<<dim3(N1q / 32, K1 / 32), 256, 0, stream>>>(W_in, WiT, K1, N1q);
  cast_f32_bf16<<<(N2 * K2 / 4 + 255) / 256, 256, 0, stream>>>(W_prj, Wpb, N2 * K2 / 4);

  gemm_bt<3><<<dim3(N1q / 128, M1 / 128), 256, 0, stream>>>(
      xb, WiT, (void*)Wx, bias, K1, N1q);

  lstm_mfma<<<dim3(16), 1024, 0, stream>>>(Wx, R, H);

  gemm_bt<0><<<dim3(N2 / 128, M1 / 128), 256, 0, stream>>>(
      H, Wpb, d_out, b_prj, K2, N2);
}

// Round 19
// 793.895 us; speedup vs baseline: 1.3755x; 1.3755x over previous
//
#include <hip/hip_runtime.h>
#include <hip/hip_bf16.h>

#define DEV __device__ __forceinline__

using bf16 = __hip_bfloat16;
typedef __attribute__((ext_vector_type(8))) short short8v;  // 8 bf16 = 4 VGPRs
typedef __attribute__((ext_vector_type(4))) float f32x4;

constexpr int Bq = 16, Tq = 1024, Eq = 1024, Gq = 4, Nq = 8, Dq = 128, Vq = 2048;
constexpr int M1 = Bq * Tq;        // 16384
constexpr int N1q = Gq * Nq * Dq;  // 4096
constexpr int K1 = Eq;             // 1024
constexpr int K2 = Nq * Dq;        // 1024
constexpr int N2 = Vq;             // 2048

DEV unsigned short bfu(float x) {
  union { bf16 h; unsigned short u; } cv;
  cv.h = __float2bfloat16(x);
  return cv.u;
}

DEV float rcp_(float x) { return __builtin_amdgcn_rcpf(x); }
DEV float sigm(float x) { return rcp_(1.0f + __expf(-x)); }
DEV float tanh_(float x) { return fmaf(2.0f, rcp_(1.0f + __expf(-2.0f * x)), -1.0f); }

// async global->LDS, 16B per lane; LDS dest is wave-uniform base + lane*16
#define GLD16(gp, lp)                                                       \
  __builtin_amdgcn_global_load_lds(                                        \
      (const __attribute__((address_space(1))) void*)(gp),                 \
      (__attribute__((address_space(3))) void*)(lp), 16, 0, 0)

#define SBAR0() __builtin_amdgcn_sched_barrier(0)
#define RAWBAR()                                                            \
  do { SBAR0(); __builtin_amdgcn_s_barrier(); SBAR0(); } while (0)
#define VMW6() asm volatile("s_waitcnt vmcnt(6)" ::: "memory")
#define VMW3() asm volatile("s_waitcnt vmcnt(3)" ::: "memory")
#define VMW0() asm volatile("s_waitcnt vmcnt(0)" ::: "memory")

// ---------------------------------------------------------------------------
// Prep kernels
// ---------------------------------------------------------------------------
__global__ __launch_bounds__(256) void cast_f32_bf16(const float* __restrict__ s,
                                                     bf16* __restrict__ d, int n4) {
  const int i = blockIdx.x * 256 + threadIdx.x;
  if (i >= n4) return;
  const float4 v = ((const float4*)s)[i];
  ushort4 u;
  u.x = bfu(v.x); u.y = bfu(v.y); u.z = bfu(v.z); u.w = bfu(v.w);
  ((ushort4*)d)[i] = u;
}

// W_in[k][c] f32 (c = g*1024+n*128+dd) -> WiT_perm[n*512 + dd*4 + g][k] bf16.
__global__ __launch_bounds__(256) void transpose_cast_perm(const float* __restrict__ s,
                                                           bf16* __restrict__ d,
                                                           int SK, int SN) {
  __shared__ float t[32][33];
  const int n0 = blockIdx.x * 32, k0 = blockIdx.y * 32;
  const int tx = threadIdx.x & 31, ty = threadIdx.x >> 5;  // ty: 0..7
#pragma unroll
  for (int i = 0; i < 32; i += 8)
    t[ty + i][tx] = s[(size_t)(k0 + ty + i) * SN + n0 + tx];
  __syncthreads();
#pragma unroll
  for (int i = 0; i < 32; i += 8) {
    const int c = n0 + ty + i;
    const int g = c >> 10, n = (c >> 7) & 7, dd = c & 127;
    const int rp = n * 512 + dd * 4 + g;
    d[(size_t)rp * SK + k0 + tx] = __float2bfloat16(t[tx][ty + i]);
  }
}

__global__ __launch_bounds__(256) void zero_flags(unsigned int* __restrict__ f) {
  f[blockIdx.x * 256 + threadIdx.x] = 0u;
}

// ---------------------------------------------------------------------------
// TRIPLE-FUSED kernel (256 WGs x 512 threads, 1 WG/CU by LDS capacity).
//   WGs 0-223  : (phase 1) pipelined gemm_xw producers (r17 structure),
//                Wx written CHUNK-MAJOR: elem = b<<22 | s<<19 | (n*128+tau)*512
//                | gd. Release wxflag[bn*8+s] (+2 per pair, target 4).
//                (phase 2) morph into logits consumers: spin hflag[b*8+s]==8,
//                compute 128x128 out tile (8-wave), f32+bias -> d_out. The
//                tile overwrites exactly the Wx chunk (b,s) that hflag
//                guarantees fully consumed -> d_out dual-use is race-free.
//   WGs 224-255: lstm consumer (r17, chunk-major wx addressing); per-chunk
//                epilogue: __syncthreads + threadfence + 4x hflag release.
// ---------------------------------------------------------------------------
__global__ __launch_bounds__(512) void fused_all(
    const bf16* __restrict__ xb, const bf16* __restrict__ WiT,
    bf16* __restrict__ WxC, const float* __restrict__ bp,
    const float* __restrict__ R, bf16* __restrict__ h_all,
    const bf16* __restrict__ Wpb, const float* __restrict__ bprj,
    float* __restrict__ out, unsigned int* wxflags, unsigned int* hflags) {
  __shared__ bf16 Ab[4][128 * 32];      // 32 KB (out phase reuses Ab[0],Ab[1])
  __shared__ bf16 Bb[4][2][128 * 32];   // 64 KB
  __shared__ __align__(16) unsigned short hl[2][4][144];

  const int bid = blockIdx.x;
  const int tid = threadIdx.x;

  if (bid < 224) {
    const int lane = tid & 63;
    const int w8 = tid >> 6;       // 0..7
    // ==================== phase 1: pipelined gemm_xw ====================
    {
      const int ts = w8 >> 2;        // tile within pair
      const int w4 = w8 & 3;
      const int wm = w4 >> 1, wn = w4 & 1;
      const int rr = lane & 15, kb = (lane >> 4) * 8;
      const int crow = (lane >> 4) * 4, ccol = lane & 15;
      const int frow = 16 * w8 + (lane >> 2);
      const int fcol = (lane & 3) * 8;
      bf16* const Adst = &Ab[0][16 * w8 * 32];
      bf16* const B0dst = &Bb[0][0][16 * w8 * 32];
      bf16* const B1dst = &Bb[0][1][16 * w8 * 32];

      for (int pi = bid; pi < 2048; pi += 224) {
        const int tix0 = pi * 2;
        const int s = tix0 >> 9;
        const int rem = tix0 & 511;
        const int bn = rem >> 2, q0 = rem & 3;
        const int b = bn >> 3, n = bn & 7;
        const int m0 = (b * 8 + s) * 128;
        const int n0base = (n * 4 + q0) * 128;

        const bf16* Asrc = xb + (size_t)(m0 + frow) * 1024 + fcol;
        const bf16* B0src = WiT + (size_t)(n0base + frow) * 1024 + fcol;
        const bf16* B1src = B0src + (size_t)128 * 1024;

#define FILLCHUNK(BUF, KC)                                                   \
  do {                                                                       \
    const size_t go_ = (size_t)(KC) * 32;                                    \
    GLD16(Asrc + go_, Adst + (BUF) * 4096);                                  \
    GLD16(B0src + go_, B0dst + (BUF) * 8192);                                \
    GLD16(B1src + go_, B1dst + (BUF) * 8192);                                \
  } while (0)

        f32x4 acc[4][4] = {};

#define COMPUTECHUNK(BUF)                                                    \
  do {                                                                       \
    const bf16* Ap_ = &Ab[(BUF)][0];                                         \
    const bf16* Bp_ = &Bb[(BUF)][ts][0];                                     \
    short8v af[4], bfr[4];                                                   \
    _Pragma("unroll") for (int i2 = 0; i2 < 4; ++i2) {                       \
      af[i2]  = *(const short8v*)&Ap_[(wm * 64 + i2 * 16 + rr) * 32 + kb];   \
      bfr[i2] = *(const short8v*)&Bp_[(wn * 64 + i2 * 16 + rr) * 32 + kb];   \
    }                                                                        \
    _Pragma("unroll") for (int i2 = 0; i2 < 4; ++i2)                         \
      _Pragma("unroll") for (int j2 = 0; j2 < 4; ++j2)                       \
        acc[i2][j2] = __builtin_amdgcn_mfma_f32_16x16x32_bf16(               \
            af[i2], bfr[j2], acc[i2][j2], 0, 0, 0);                          \
  } while (0)

        FILLCHUNK(0, 0);
        FILLCHUNK(1, 1);
        for (int i = 0; i < 30; ++i) {
          FILLCHUNK((i + 2) & 3, i + 2);
          VMW6();
          RAWBAR();
          COMPUTECHUNK(i & 3);
        }
        VMW3();
        RAWBAR();
        COMPUTECHUNK(2);
        VMW0();
        RAWBAR();
        COMPUTECHUNK(3);

        // epilogue: CHUNK-MAJOR Wx (bias folded), coalesced over gd
        {
          const int n0t = n0base + ts * 128;
#pragma unroll
          for (int i = 0; i < 4; ++i)
#pragma unroll
            for (int j = 0; j < 4; ++j) {
              const int pc = n0t + wn * 64 + j * 16 + ccol;
              const int nn = pc >> 9, gd = pc & 511;
              const int g = gd & 3, dd = gd >> 2;
              const float bvj = bp[(g * 8 + nn) * 128 + dd];
#pragma unroll
              for (int jj = 0; jj < 4; ++jj) {
                const int row = m0 + wm * 64 + i * 16 + crow + jj;
                const int bb = row >> 10, ss = (row >> 7) & 7, tau = row & 127;
                const size_t idx = ((size_t)bb << 22) + ((size_t)ss << 19) +
                                   ((size_t)(nn * 128 + tau) << 9) + gd;
                WxC[idx] = __float2bfloat16(acc[i][j][jj] + bvj);
              }
            }
        }
        __syncthreads();  // drains all waves' stores (vmcnt 0 before barrier)
        if (tid == 0) {
          __threadfence();
          __hip_atomic_fetch_add(&wxflags[bn * 8 + s], 2u,
                                 __ATOMIC_RELEASE, __HIP_MEMORY_SCOPE_AGENT);
        }
      }
#undef FILLCHUNK
#undef COMPUTECHUNK
    }
    // ==================== phase 2: logits consumer ====================
    {
      bf16* const AsO = &Ab[0][0];   // 128x32
      bf16* const BsO = &Ab[1][0];   // 128x32
      const int wm2 = w8 >> 2, wn2 = w8 & 3;
      const int srow = lane >> 2, scol = (lane & 3) * 8;
      const int rr = lane & 15, kb = (lane >> 4) * 8;
      const int crow = (lane >> 4) * 4, ccol = lane & 15;
      __syncthreads();  // all waves left phase 1 LDS

      for (int oi = bid; oi < 2048; oi += 224) {
        const int so = oi >> 8;
        const int rem = oi & 255;
        const int bo = rem >> 4, nc = rem & 15;
        const int m0 = bo * 1024 + so * 128;
        const int n0 = nc * 128;

        if (tid == 0) {
          while (__hip_atomic_load(&hflags[bo * 8 + so], __ATOMIC_RELAXED,
                                   __HIP_MEMORY_SCOPE_AGENT) < 8u)
            __builtin_amdgcn_s_sleep(16);
          __threadfence();
        }
        __syncthreads();

        f32x4 acc[4][2] = {};
        const bf16* Ag = h_all + (size_t)(m0 + 16 * w8 + srow) * 1024 + scol;
        const bf16* Bg = Wpb + (size_t)(n0 + 16 * w8 + srow) * 1024 + scol;
        for (int k0 = 0; k0 < 1024; k0 += 32) {
          GLD16(Ag + k0, AsO + w8 * 512);
          GLD16(Bg + k0, BsO + w8 * 512);
          __syncthreads();
          short8v af[4], bfr[2];
#pragma unroll
          for (int i = 0; i < 4; ++i)
            af[i] = *(const short8v*)&AsO[(wm2 * 64 + i * 16 + rr) * 32 + kb];
#pragma unroll
          for (int j = 0; j < 2; ++j)
            bfr[j] = *(const short8v*)&BsO[(wn2 * 32 + j * 16 + rr) * 32 + kb];
#pragma unroll
          for (int i = 0; i < 4; ++i)
#pragma unroll
            for (int j = 0; j < 2; ++j)
              acc[i][j] = __builtin_amdgcn_mfma_f32_16x16x32_bf16(
                  af[i], bfr[j], acc[i][j], 0, 0, 0);
          __syncthreads();
        }
        float bv[2];
#pragma unroll
        for (int j = 0; j < 2; ++j) bv[j] = bprj[n0 + wn2 * 32 + j * 16 + ccol];
#pragma unroll
        for (int i = 0; i < 4; ++i)
#pragma unroll
          for (int j = 0; j < 2; ++j) {
            const size_t base =
                (size_t)(m0 + wm2 * 64 + i * 16 + crow) * N2 +
                (n0 + wn2 * 32 + j * 16 + ccol);
#pragma unroll
            for (int jj = 0; jj < 4; ++jj)
              out[base + (size_t)jj * N2] = acc[i][j][jj] + bv[j];
          }
        __syncthreads();
      }
    }
  } else {
    // ==================== lstm consumer (r17 + hflag release) ================
    const int cid = bid - 224;
    const int n = cid & 7, bq = cid >> 3;
    const int w = tid >> 6, lane = tid & 63;
    const int lg = lane >> 4, lc = lane & 15;
    const int bloc = lc & 3;
    const int ci = lc >> 2;
    const int dsite = 16 * w + 4 * ci + lg;
    const int b = bq * 4 + bloc;

    short8v Af[4][4];
#pragma unroll
    for (int tau = 0; tau < 4; ++tau) {
      const int gd = 64 * w + 16 * tau + lc;
      const int g = gd & 3, d = gd >> 2;
      const float* rbase = R + ((size_t)(g * 8 + n) * 128 + d) * 128;
#pragma unroll
      for (int kf = 0; kf < 4; ++kf) {
        const float* rp = rbase + 32 * kf + 8 * lg;
        const float4 r0 = *(const float4*)rp;
        const float4 r1 = *(const float4*)(rp + 4);
        short8v bv;
        bv[0] = (short)bfu(r0.x); bv[1] = (short)bfu(r0.y);
        bv[2] = (short)bfu(r0.z); bv[3] = (short)bfu(r0.w);
        bv[4] = (short)bfu(r1.x); bv[5] = (short)bfu(r1.y);
        bv[6] = (short)bfu(r1.z); bv[7] = (short)bfu(r1.w);
        Af[tau][kf] = bv;
      }
    }

    for (int i = tid; i < 4 * 144; i += 512) (&hl[0][0][0])[i] = 0;
    __syncthreads();

    bf16* hout = h_all + ((size_t)b << 20) + n * 128 + dsite;
    float c = 0.f;

    for (int s = 0; s < 8; ++s) {
      if (tid == 0) {
#pragma unroll
        for (int j = 0; j < 4; ++j) {
          const int fidx = ((bq * 4 + j) * 8 + n) * 8 + s;
          while (__hip_atomic_load(&wxflags[fidx], __ATOMIC_RELAXED,
                                   __HIP_MEMORY_SCOPE_AGENT) < 4u)
            __builtin_amdgcn_s_sleep(2);
        }
        __threadfence();
      }
      __syncthreads();

      // chunk-major wx base for this (b, s, n, dsite)
      const bf16* wxs = WxC + ((size_t)b << 22) + ((size_t)s << 19) +
                        ((size_t)(n * 128) << 9) + dsite * 4;

      ushort4 wxr[4];
#pragma unroll
      for (int u = 0; u < 4; ++u)
        wxr[u] = *(const ushort4*)(wxs + (size_t)u * 512);

      for (int tau0 = 0; tau0 < 128; tau0 += 4) {
#pragma unroll
        for (int u = 0; u < 4; ++u) {
          const int tau = tau0 + u;
          const int t = s * 128 + tau;
          const unsigned short* hb = &hl[t & 1][0][0];
          short8v Bf[4];
#pragma unroll
          for (int kf = 0; kf < 4; ++kf)
            Bf[kf] = *(const short8v*)(hb + bloc * 144 + kf * 32 + lg * 8);

          const ushort4 wxc = wxr[u];  // capture before overwrite (r11 lesson)

          f32x4 acc[4];
#pragma unroll
          for (int tt = 0; tt < 4; ++tt) {
            acc[tt][0] = 0.f; acc[tt][1] = 0.f;
            acc[tt][2] = 0.f; acc[tt][3] = 0.f;
          }
#pragma unroll
          for (int kf = 0; kf < 4; ++kf)
#pragma unroll
            for (int tt = 0; tt < 4; ++tt)
              acc[tt] = __builtin_amdgcn_mfma_f32_16x16x32_bf16(
                  Af[tt][kf], Bf[kf], acc[tt], 0, 0, 0);

          {
            const int tp = (tau + 4 < 128) ? (tau + 4) : 127;
            wxr[u] = *(const ushort4*)(wxs + (size_t)tp * 512);
          }

          float pre0 = (ci & 2) ? ((ci & 1) ? acc[3][0] : acc[2][0])
                                : ((ci & 1) ? acc[1][0] : acc[0][0]);
          float pre1 = (ci & 2) ? ((ci & 1) ? acc[3][1] : acc[2][1])
                                : ((ci & 1) ? acc[1][1] : acc[0][1]);
          float pre2 = (ci & 2) ? ((ci & 1) ? acc[3][2] : acc[2][2])
                                : ((ci & 1) ? acc[1][2] : acc[0][2]);
          float pre3 = (ci & 2) ? ((ci & 1) ? acc[3][3] : acc[2][3])
                                : ((ci & 1) ? acc[1][3] : acc[0][3]);
          pre0 += __uint_as_float((unsigned)wxc.x << 16);
          pre1 += __uint_as_float((unsigned)wxc.y << 16);
          pre2 += __uint_as_float((unsigned)wxc.z << 16);
          pre3 += __uint_as_float((unsigned)wxc.w << 16);

          const float i_ = sigm(pre0);
          const float f_ = sigm(pre1);
          const float z_ = tanh_(pre2);
          const float o_ = sigm(pre3);
          c = f_ * c + i_ * z_;
          const float h = o_ * tanh_(c);
          const bf16 h16 = __float2bfloat16(h);

          hl[(t + 1) & 1][bloc][dsite] = ((const unsigned short*)&h16)[0];
          hout[(size_t)t << 10] = h16;

          __builtin_amdgcn_sched_barrier(0);
          asm volatile("s_waitcnt lgkmcnt(0)" ::: "memory");
          __builtin_amdgcn_sched_barrier(0);
          __builtin_amdgcn_s_barrier();
          __builtin_amdgcn_sched_barrier(0);
        }
      }

      // chunk done: publish H chunk for the out-phase consumers
      __syncthreads();  // drain h_all stores (vmcnt 0)
      if (tid == 0) {
        __threadfence();
#pragma unroll
        for (int j = 0; j < 4; ++j)
          __hip_atomic_fetch_add(&hflags[(bq * 4 + j) * 8 + s], 1u,
                                 __ATOMIC_RELEASE, __HIP_MEMORY_SCOPE_AGENT);
      }
    }
  }
}

// ---------------------------------------------------------------------------
extern "C" void kernel_launch(void* const* d_in, const int* in_sizes, int n_in,
                              void* d_out, int out_size, void* d_ws, size_t ws_size,
                              hipStream_t stream) {
  const float* x_emb = (const float*)d_in[0];  // [16,1024,1024]
  const float* W_in  = (const float*)d_in[1];  // [1024,4096]
  const float* R     = (const float*)d_in[2];  // [4,8,128,128]
  const float* bias  = (const float*)d_in[3];  // [4,8,128]
  const float* W_prj = (const float*)d_in[4];  // [2048,1024]
  const float* b_prj = (const float*)d_in[5];  // [2048]

  char* ws = (char*)d_ws;
  bf16* xb  = (bf16*)ws;                               // 32 MB
  bf16* WiT = (bf16*)(ws + (size_t)M1 * K1 * 2);       //  8 MB (row-permuted)
  bf16* Wpb = WiT + (size_t)N1q * K1;                  //  4 MB
  bf16* H   = Wpb + (size_t)N2 * K2;                   // 32 MB
  unsigned int* flags = (unsigned int*)(ws + ((size_t)76 << 20));  // 6 KB
  unsigned int* wxflags = flags;          // 1024 entries
  unsigned int* hflags  = flags + 1024;   // 128 entries
  bf16* Wx = (bf16*)d_out;  // 134 MB chunk-major [b][s][n,tau,gd]

  cast_f32_bf16<<<(M1 * K1 / 4 + 255) / 256, 256, 0, stream>>>(x_emb, xb, M1 * K1 / 4);
  transpose_cast_perm<<<dim3(N1q / 32, K1 / 32), 256, 0, stream>>>(W_in, WiT, K1, N1q);
  cast_f32_bf16<<<(N2 * K2 / 4 + 255) / 256, 256, 0, stream>>>(W_prj, Wpb, N2 * K2 / 4);
  zero_flags<<<5, 256, 0, stream>>>(flags);

  fused_all<<<dim3(256), dim3(512), 0, stream>>>(
      xb, WiT, Wx, bias, R, H, Wpb, b_prj, (float*)d_out, wxflags, hflags);
}